// Round 3
// baseline (466.719 us; speedup 1.0000x reference)
//
#include <hip/hip_runtime.h>
#include <cmath>

// QuanvolutionSelfAttentionClassifier on MI355X — round 3.
//
// Algebra (verified by R1/R2 passes): softmax over length-1 axis == 1 ->
// attn_weights == mean_embeds (rotation/entangle params dead). With
// l = c*196 + p, embedding index d = p & 3.
//   logits[j] = lin_b[j] + sum_d M[d] * (cst[d][j] + T[d][j])
//   M[d]    = a + sum_pix x[pix]*gm(pix),  a = sum_c conv_b[c]/4
//   T[d][j] = sum_{pix: d(pix)==d} x[pix] * G[pix][j]
// pixel (r,cc): d = (2*((r>>1)&1) + (cc>>1)) & 3.
//
// R2 failed on register pressure (44 accs/thread -> scratch, 87 MB spill
// writes). v3 splits the 44 output COLUMNS across the 4 waves (12 accs each)
// instead of splitting rows; rows are staged once into block-shared LDS
// planes so HBM traffic stays 1x. Wave w consumes G-slice w (prep kernel
// repacks G into Gs[4][784][4]; wave 3's slice = {j9, gm, 0, 0} so all waves
// run identical 3-FMA-per-pixel code; acc[d][1] of wave 3 is mu[d]).
//
// Staging: 3 LDS planes [64][36] floats; 256 threads cooperatively stage one
// 28-float row for all 64 samples per step (thread t owns chunk t and t+256);
// 3-deep register pipeline (load row i+5 while writing row i+2, consuming
// row i). Raw s_barrier + manual lgkmcnt(0) per row (NOT __syncthreads: its
// vmcnt(0) drain would serialize the global prefetch). Fully unrolled so all
// slot/plane/parity indices are compile-time.

#define GS_STRIDE 3136   // floats per wave G-slice (784*4)
#define WS_A      12544
#define WS_CST    12545  // 40 floats

__global__ void qsac_prep(const float* __restrict__ cw, const float* __restrict__ cb,
                          const float* __restrict__ lw, float* __restrict__ ws) {
  const int t = blockIdx.x * 98 + threadIdx.x;  // 8 x 98 = 784 pixels
  const int r = t / 28, cc = t - r * 28;
  const int kh = r & 1, kw = cc & 1;
  const int p = (r >> 1) * 14 + (cc >> 1);
  const float w0 = cw[(kh << 1) + kw],     w1 = cw[4 + (kh << 1) + kw],
              w2 = cw[8 + (kh << 1) + kw], w3 = cw[12 + (kh << 1) + kw];
  float g[10];
#pragma unroll
  for (int j = 0; j < 10; ++j)
    g[j] = w0 * lw[j * 784 + p]       + w1 * lw[j * 784 + 196 + p] +
           w2 * lw[j * 784 + 392 + p] + w3 * lw[j * 784 + 588 + p];
  const float gm = (w0 + w1 + w2 + w3) * (1.0f / 196.0f);
  *reinterpret_cast<float4*>(ws + 0 * GS_STRIDE + t * 4) = make_float4(g[0], g[1], g[2], 0.f);
  *reinterpret_cast<float4*>(ws + 1 * GS_STRIDE + t * 4) = make_float4(g[3], g[4], g[5], 0.f);
  *reinterpret_cast<float4*>(ws + 2 * GS_STRIDE + t * 4) = make_float4(g[6], g[7], g[8], 0.f);
  *reinterpret_cast<float4*>(ws + 3 * GS_STRIDE + t * 4) = make_float4(g[9], gm,   0.f,  0.f);

  if (blockIdx.x == 0) {
    const int u = threadIdx.x;
    if (u < 40) {
      const int d = u / 10, j = u - (u / 10) * 10;
      const float b0 = cb[0], b1 = cb[1], b2 = cb[2], b3 = cb[3];
      float s = 0.f;
#pragma unroll 7
      for (int q = d; q < 196; q += 4)
        s += b0 * lw[j * 784 + q]       + b1 * lw[j * 784 + 196 + q] +
             b2 * lw[j * 784 + 392 + q] + b3 * lw[j * 784 + 588 + q];
      ws[WS_CST + u] = s;
    } else if (u == 40) {
      ws[WS_A] = (cb[0] + cb[1] + cb[2] + cb[3]) * 0.25f;
    }
  }
}

// One pixel: 1 uniform G float4 (s_load) + 3 FMAs into static acc slots.
#define PIX1(ROW, PAR, CC, XV)                                                \
  {                                                                           \
    constexpr int dd_ = (2 * (PAR) + ((CC) >> 1)) & 3;                        \
    const float4 g_ =                                                         \
        *reinterpret_cast<const float4*>(Gw + ((ROW) * 28 + (CC)) * 4);       \
    acc[dd_][0] += (XV)*g_.x;                                                 \
    acc[dd_][1] += (XV)*g_.y;                                                 \
    acc[dd_][2] += (XV)*g_.z;                                                 \
  }

#define PIXGRP(ROW, PAR, MM)                                                  \
  {                                                                           \
    const float4 t_ = *reinterpret_cast<const float4*>(rp + (MM)*4);          \
    PIX1(ROW, PAR, 4 * (MM) + 0, t_.x)                                        \
    PIX1(ROW, PAR, 4 * (MM) + 1, t_.y)                                        \
    PIX1(ROW, PAR, 4 * (MM) + 2, t_.z)                                        \
    PIX1(ROW, PAR, 4 * (MM) + 3, t_.w)                                        \
  }

// Row step: ds_write row ROW+2 (slot (ROW+2)%3), reload that slot with row
// ROW+5, consume row ROW from plane ROW%3, then lgkm-drain + raw barrier.
// Plane reuse safety: plane (ROW+2)%3 was last read at step ROW-1, which
// completed before the barrier ending step ROW-1; our write is after it.
#define RS(ROW)                                                               \
  {                                                                           \
    constexpr int SW = ((ROW) + 2) % 3;                                       \
    if constexpr ((ROW) + 2 < 28) {                                           \
      float* wp = smem + SW * 2304;                                           \
      *reinterpret_cast<float4*>(wp + wadr1) = R[SW][0];                      \
      if (has2) *reinterpret_cast<float4*>(wp + wadr2) = R[SW][1];            \
      if constexpr ((ROW) + 5 < 28) {                                         \
        R[SW][0] = *reinterpret_cast<const float4*>(xg1 + ((ROW) + 5) * 28);  \
        if (has2)                                                             \
          R[SW][1] = *reinterpret_cast<const float4*>(xg2 + ((ROW) + 5) * 28);\
      }                                                                       \
    }                                                                         \
    constexpr int PL = (ROW) % 3;                                             \
    constexpr int PAR = ((ROW) >> 1) & 1;                                     \
    const float* rp = smem + PL * 2304 + lane * 36;                           \
    PIXGRP(ROW, PAR, 0) PIXGRP(ROW, PAR, 1) PIXGRP(ROW, PAR, 2)               \
    PIXGRP(ROW, PAR, 3) PIXGRP(ROW, PAR, 4) PIXGRP(ROW, PAR, 5)               \
    PIXGRP(ROW, PAR, 6)                                                       \
    asm volatile("s_waitcnt lgkmcnt(0)" ::: "memory");                        \
    __builtin_amdgcn_s_barrier();                                             \
    asm volatile("" ::: "memory");                                            \
  }

__global__ __launch_bounds__(256, 2) void qsac_main(
    const float* __restrict__ x, const float* __restrict__ ws,
    const float* __restrict__ lin_b, float* __restrict__ out) {
  // 3 planes [64][36] floats + M[256] + L[64*12] = 7936 floats (31.7 KB)
  __shared__ float smem[3 * 2304 + 256 + 768];

  const int tid = threadIdx.x;
  const int lane = tid & 63;
  const int wid = __builtin_amdgcn_readfirstlane(tid >> 6);
  const int sbase = blockIdx.x * 64;
  const float* __restrict__ Gw = ws + wid * GS_STRIDE;  // uniform -> s_load

  // Cooperative staging: thread t owns chunk t (always) and t+256 (t<192).
  // Chunk c -> sample s = c/7, 16B-piece m = c%7.
  const int s1 = tid / 7, m1 = tid - s1 * 7;
  const bool has2 = tid < 192;
  const int c2 = tid + 256;
  const int s2r = c2 / 7, m2 = c2 - s2r * 7;
  const int s2 = has2 ? s2r : 0;  // clamp (never dereferenced when !has2)
  const float* xg1 = x + (size_t)(sbase + s1) * 784 + m1 * 4;
  const float* xg2 = x + (size_t)(sbase + s2) * 784 + m2 * 4;
  const int wadr1 = s1 * 36 + m1 * 4;
  const int wadr2 = s2r * 36 + m2 * 4;

  float acc[4][3];
#pragma unroll
  for (int d = 0; d < 4; ++d)
#pragma unroll
    for (int q = 0; q < 3; ++q) acc[d][q] = 0.f;

  // Prologue: rows 0,1,2 -> slots 0,1,2; write rows 0,1; reload slots 0,1
  // with rows 3,4. (Compiler inserts the vmcnt waits before each ds_write.)
  float4 R[3][2];
  R[0][0] = *reinterpret_cast<const float4*>(xg1 + 0 * 28);
  R[1][0] = *reinterpret_cast<const float4*>(xg1 + 1 * 28);
  R[2][0] = *reinterpret_cast<const float4*>(xg1 + 2 * 28);
  if (has2) {
    R[0][1] = *reinterpret_cast<const float4*>(xg2 + 0 * 28);
    R[1][1] = *reinterpret_cast<const float4*>(xg2 + 1 * 28);
    R[2][1] = *reinterpret_cast<const float4*>(xg2 + 2 * 28);
  }
  *reinterpret_cast<float4*>(smem + 0 * 2304 + wadr1) = R[0][0];
  *reinterpret_cast<float4*>(smem + 1 * 2304 + wadr1) = R[1][0];
  if (has2) {
    *reinterpret_cast<float4*>(smem + 0 * 2304 + wadr2) = R[0][1];
    *reinterpret_cast<float4*>(smem + 1 * 2304 + wadr2) = R[1][1];
  }
  R[0][0] = *reinterpret_cast<const float4*>(xg1 + 3 * 28);
  R[1][0] = *reinterpret_cast<const float4*>(xg1 + 4 * 28);
  if (has2) {
    R[0][1] = *reinterpret_cast<const float4*>(xg2 + 3 * 28);
    R[1][1] = *reinterpret_cast<const float4*>(xg2 + 4 * 28);
  }
  asm volatile("s_waitcnt lgkmcnt(0)" ::: "memory");
  __builtin_amdgcn_s_barrier();
  asm volatile("" ::: "memory");

  RS(0)  RS(1)  RS(2)  RS(3)  RS(4)  RS(5)  RS(6)
  RS(7)  RS(8)  RS(9)  RS(10) RS(11) RS(12) RS(13)
  RS(14) RS(15) RS(16) RS(17) RS(18) RS(19) RS(20)
  RS(21) RS(22) RS(23) RS(24) RS(25) RS(26) RS(27)

  // ---- epilogue ----
  float* Mld = smem + 3 * 2304;        // [64][4]
  float* L   = smem + 3 * 2304 + 256;  // [64][12]

  if (wid == 3) {
    const float a = ws[WS_A];
#pragma unroll
    for (int d = 0; d < 4; ++d) Mld[lane * 4 + d] = a + acc[d][1];
  }
  __syncthreads();

  float M[4];
#pragma unroll
  for (int d = 0; d < 4; ++d) M[d] = Mld[lane * 4 + d];

#pragma unroll
  for (int q = 0; q < 3; ++q) {
    if (wid < 3 || q == 0) {
      const int j = 3 * wid + q;  // wid 3, q 0 -> j 9
      float v = lin_b[j];
#pragma unroll
      for (int d = 0; d < 4; ++d)
        v += M[d] * (ws[WS_CST + d * 10 + j] + acc[d][q]);
      L[lane * 12 + j] = v;
    }
  }
  __syncthreads();

  if (wid == 0) {
    float logits[10];
#pragma unroll
    for (int j = 0; j < 10; ++j) logits[j] = L[lane * 12 + j];
    float mx = logits[0];
#pragma unroll
    for (int j = 1; j < 10; ++j) mx = fmaxf(mx, logits[j]);
    float se = 0.f;
#pragma unroll
    for (int j = 0; j < 10; ++j) se += __expf(logits[j] - mx);
    const float lse = mx + __logf(se);
    float* op = out + (size_t)(sbase + lane) * 10;
#pragma unroll
    for (int j = 0; j < 10; ++j) op[j] = logits[j] - lse;
  }
}

extern "C" void kernel_launch(void* const* d_in, const int* in_sizes, int n_in,
                              void* d_out, int out_size, void* d_ws, size_t ws_size,
                              hipStream_t stream) {
  (void)n_in; (void)ws_size; (void)out_size;
  const float* x = (const float*)d_in[0];
  const float* conv_w = (const float*)d_in[1];
  const float* conv_b = (const float*)d_in[2];
  // d_in[3]/d_in[4] (rotation/entangle) are dead: softmax over length-1 == 1.
  const float* lin_w = (const float*)d_in[5];
  const float* lin_b = (const float*)d_in[6];
  float* out = (float*)d_out;
  float* ws = (float*)d_ws;

  hipLaunchKernelGGL(qsac_prep, dim3(8), dim3(98), 0, stream,
                     conv_w, conv_b, lin_w, ws);

  const int B = in_sizes[0] / 784;  // 32768
  const int nblk = B / 64;          // 512 blocks x 256 threads
  hipLaunchKernelGGL(qsac_main, dim3(nblk), dim3(256), 0, stream,
                     x, ws, lin_b, out);
}

// Round 5
// 87.489 us; speedup vs baseline: 5.3346x; 5.3346x over previous
//
#include <hip/hip_runtime.h>
#include <cmath>

// QuanvolutionSelfAttentionClassifier on MI355X — round 5.
//
// Algebra (verified by R1-R3 passes): softmax over length-1 axis == 1 ->
// attn_weights == mean_embeds (rotation/entangle params dead). With
// l = c*196 + p, embedding index d = p & 3; for input pixel (r,cc):
// d = (2*((r>>1)&1) + (cc>>1)) & 3.
//   logits[j] = lin_b[j] + sum_d M[d] * (cst[d][j] + T[d][j])
//   M[d]    = a + sum_pix x[pix]*gm(pix),   a = sum_c conv_b[c]/4
//   T[d][j] = sum_{pix: d(pix)==d} x[pix] * G[pix][j]
//
// R4 bug: x staging covered only 112 of the 448 float4 chunks per row ->
// 3/4 of each plane was uninitialized LDS. v5 fixes coverage (c1=tid for all
// 256 threads, c2=tid+256 for tid<192 — wave-uniform predicate) and moves G
// back to wave-uniform GLOBAL reads (s_load path, as in the numerically-good
// R2): broadcast ds_reads of G would cost more LDS-pipe cycles than the HBM
// floor, while s_loads hit K$/L2 at zero VGPR cost. R3's global-G spill
// disaster came from its 28-step full unroll; here the unroll-1 loop with
// per-step asm barriers bounds live ranges (live state ~105 VGPR).
//
// Waves: wid = ch*2 + rh. ch = column half (ch0: j=0..4, ch1: j=5..9+mean),
// rh = row parity (computes rows r with r&1==rh). Period-4 pipeline over 4
// LDS planes [64][36]: at step for row r, stage row r+3 into plane (r+3)%4,
// prefetch row r+7 into R*, matching-rh waves compute 14 pixel-pairs
// (3 uniform s_load dwordx4 + 12 FMA each). Raw s_barrier + lgkmcnt(0)-only
// drain keeps global x prefetch in flight across barriers.

#define WS_A    9408
#define WS_CST  9409

__global__ void qsac_prep(const float* __restrict__ cw, const float* __restrict__ cb,
                          const float* __restrict__ lw, float* __restrict__ ws) {
  const int t = blockIdx.x * 98 + threadIdx.x;  // 8 x 98 = 784 pixels
  const int r = t / 28, cc = t - r * 28;
  const int kh = r & 1, kw = cc & 1;
  const int p = (r >> 1) * 14 + (cc >> 1);
  const float w0 = cw[(kh << 1) + kw],     w1 = cw[4 + (kh << 1) + kw],
              w2 = cw[8 + (kh << 1) + kw], w3 = cw[12 + (kh << 1) + kw];
  float g[10];
#pragma unroll
  for (int j = 0; j < 10; ++j)
    g[j] = w0 * lw[j * 784 + p]       + w1 * lw[j * 784 + 196 + p] +
           w2 * lw[j * 784 + 392 + p] + w3 * lw[j * 784 + 588 + p];
  const float gm = (w0 + w1 + w2 + w3) * (1.0f / 196.0f);
  // Pair packing: [ch][row][pair pr=cc>>1][12] = {A: 6 floats, B: 6 floats},
  // e = cc&1 selects A/B half. ch0 slot5 = 0; ch1 slot5 = gm (mean weight).
  const int pr = cc >> 1, e = cc & 1;
  float* d0 = ws + r * 168 + pr * 12 + e * 6;
  d0[0] = g[0]; d0[1] = g[1]; d0[2] = g[2]; d0[3] = g[3]; d0[4] = g[4]; d0[5] = 0.f;
  float* d1 = ws + 4704 + r * 168 + pr * 12 + e * 6;
  d1[0] = g[5]; d1[1] = g[6]; d1[2] = g[7]; d1[3] = g[8]; d1[4] = g[9]; d1[5] = gm;

  if (blockIdx.x == 0) {
    const int u = threadIdx.x;
    if (u < 40) {
      const int d = u / 10, j = u - (u / 10) * 10;
      const float b0 = cb[0], b1 = cb[1], b2 = cb[2], b3 = cb[3];
      float s = 0.f;
#pragma unroll 7
      for (int q = d; q < 196; q += 4)
        s += b0 * lw[j * 784 + q]       + b1 * lw[j * 784 + 196 + q] +
             b2 * lw[j * 784 + 392 + q] + b3 * lw[j * 784 + 588 + q];
      ws[WS_CST + u] = s;
    } else if (u == 40) {
      ws[WS_A] = (cb[0] + cb[1] + cb[2] + cb[3]) * 0.25f;
    }
  }
}

#define BAR()                                            \
  asm volatile("s_waitcnt lgkmcnt(0)" ::: "memory");     \
  __builtin_amdgcn_s_barrier();                          \
  asm volatile("" ::: "memory");

// One pixel-pair P (cols 2P,2P+1, shared d-class): 3 wave-uniform G loads
// (s_load_dwordx4 from K$) + 12 FMAs into static acc slots.
#define PAIRX(P, PAR, XA, XB)                                                 \
  {                                                                           \
    constexpr int DD = (2 * (PAR) + ((P)&3)) & 3;                             \
    const float4 q0 = *reinterpret_cast<const float4*>(gr + (P)*12);          \
    const float4 q1 = *reinterpret_cast<const float4*>(gr + (P)*12 + 4);      \
    const float4 q2 = *reinterpret_cast<const float4*>(gr + (P)*12 + 8);      \
    acc[DD][0] += (XA)*q0.x; acc[DD][1] += (XA)*q0.y; acc[DD][2] += (XA)*q0.z;\
    acc[DD][3] += (XA)*q0.w; acc[DD][4] += (XA)*q1.x; acc[DD][5] += (XA)*q1.y;\
    acc[DD][0] += (XB)*q1.z; acc[DD][1] += (XB)*q1.w; acc[DD][2] += (XB)*q2.x;\
    acc[DD][3] += (XB)*q2.y; acc[DD][4] += (XB)*q2.z; acc[DD][5] += (XB)*q2.w;\
  }

#define MMBLK(MM, PAR)                                                        \
  {                                                                           \
    const float4 tv = *reinterpret_cast<const float4*>(rp + (MM)*4);          \
    PAIRX(2 * (MM), PAR, tv.x, tv.y)                                          \
    PAIRX(2 * (MM) + 1, PAR, tv.z, tv.w)                                      \
  }

// Step S (0..3): row r_ = rb+S (plane r_%4 == S since rb%4==0).
#define STEP(S)                                                               \
  {                                                                           \
    const int r_ = rb + (S);                                                  \
    if (r_ + 3 < 28) {                                                        \
      float* wp = smem + (((S) + 3) & 3) * 2304;                              \
      *reinterpret_cast<float4*>(wp + wadr1) = R1[((S) + 3) & 3];             \
      if (has2) *reinterpret_cast<float4*>(wp + wadr2) = R2[((S) + 3) & 3];   \
      if (r_ + 7 < 28) {                                                      \
        R1[((S) + 3) & 3] =                                                   \
            *reinterpret_cast<const float4*>(xg1 + (r_ + 7) * 28);            \
        if (has2)                                                             \
          R2[((S) + 3) & 3] =                                                 \
              *reinterpret_cast<const float4*>(xg2 + (r_ + 7) * 28);          \
      }                                                                       \
    }                                                                         \
    if (rh == ((S)&1)) {                                                      \
      const float* rp = smem + ((S)&3) * 2304 + lane36;                       \
      const float* gr = Gch + r_ * 168;                                       \
      MMBLK(0, ((S) >> 1) & 1) MMBLK(1, ((S) >> 1) & 1)                       \
      MMBLK(2, ((S) >> 1) & 1) MMBLK(3, ((S) >> 1) & 1)                       \
      MMBLK(4, ((S) >> 1) & 1) MMBLK(5, ((S) >> 1) & 1)                       \
      MMBLK(6, ((S) >> 1) & 1)                                                \
    }                                                                         \
    BAR()                                                                     \
  }

__global__ __launch_bounds__(256, 2) void qsac_main(
    const float* __restrict__ x, const float* __restrict__ ws,
    const float* __restrict__ lin_b, float* __restrict__ out) {
  __shared__ float smem[4 * 2304];  // 36.9 KB: 4 x-planes [64][36]

  const int tid = threadIdx.x;
  const int lane = tid & 63;
  const int wid = __builtin_amdgcn_readfirstlane(tid >> 6);
  const int ch = wid >> 1, rh = wid & 1;
  const int sbase = blockIdx.x * 64;
  const int lane36 = lane * 36;
  const float* __restrict__ Gch = ws + ch * 4704;  // wave-uniform -> s_load

  // x staging: chunk c -> sample s=c/7, 16B-piece m=c%7. c1 = tid (all),
  // c2 = tid+256 (tid<192; wave-uniform since 192 = 3*64). 448 chunks/row.
  const int s1 = tid / 7, m1 = tid - s1 * 7;
  const bool has2 = tid < 192;
  const int c2 = tid + 256;
  const int s2 = c2 / 7, m2 = c2 - s2 * 7;
  const float* xg1 = x + (size_t)(sbase + s1) * 784 + m1 * 4;
  const float* xg2 = x + (size_t)(sbase + (has2 ? s2 : 0)) * 784 + m2 * 4;
  const int wadr1 = s1 * 36 + m1 * 4;
  const int wadr2 = s2 * 36 + m2 * 4;

  // Prologue: rows 0-2 -> planes 0-2; rows 3-6 -> R*[3],R*[0],R*[1],R*[2].
  float4 R1[4], R2[4];
  float4 a0 = *reinterpret_cast<const float4*>(xg1);
  float4 a1 = *reinterpret_cast<const float4*>(xg1 + 28);
  float4 a2 = *reinterpret_cast<const float4*>(xg1 + 56);
  float4 b0, b1, b2;
  if (has2) {
    b0 = *reinterpret_cast<const float4*>(xg2);
    b1 = *reinterpret_cast<const float4*>(xg2 + 28);
    b2 = *reinterpret_cast<const float4*>(xg2 + 56);
  }
  R1[3] = *reinterpret_cast<const float4*>(xg1 + 3 * 28);
  R1[0] = *reinterpret_cast<const float4*>(xg1 + 4 * 28);
  R1[1] = *reinterpret_cast<const float4*>(xg1 + 5 * 28);
  R1[2] = *reinterpret_cast<const float4*>(xg1 + 6 * 28);
  if (has2) {
    R2[3] = *reinterpret_cast<const float4*>(xg2 + 3 * 28);
    R2[0] = *reinterpret_cast<const float4*>(xg2 + 4 * 28);
    R2[1] = *reinterpret_cast<const float4*>(xg2 + 5 * 28);
    R2[2] = *reinterpret_cast<const float4*>(xg2 + 6 * 28);
  }
  *reinterpret_cast<float4*>(smem + 0 * 2304 + wadr1) = a0;
  *reinterpret_cast<float4*>(smem + 1 * 2304 + wadr1) = a1;
  *reinterpret_cast<float4*>(smem + 2 * 2304 + wadr1) = a2;
  if (has2) {
    *reinterpret_cast<float4*>(smem + 0 * 2304 + wadr2) = b0;
    *reinterpret_cast<float4*>(smem + 1 * 2304 + wadr2) = b1;
    *reinterpret_cast<float4*>(smem + 2 * 2304 + wadr2) = b2;
  }
  BAR()

  float acc[4][6];
#pragma unroll
  for (int d = 0; d < 4; ++d)
#pragma unroll
    for (int q = 0; q < 6; ++q) acc[d][q] = 0.f;

#pragma unroll 1
  for (int it = 0; it < 7; ++it) {
    const int rb = it * 4;
    STEP(0) STEP(1) STEP(2) STEP(3)
  }

  // ---- epilogue (planes dead; overlay Red [0,3072) / Mld [3072,3328) /
  // L [3328,4096) — all reads of planes completed before the last BAR) ----
  if (rh == 1) {
    float* rd = smem + ch * 1536 + lane * 24;
#pragma unroll
    for (int d = 0; d < 4; ++d)
#pragma unroll
      for (int q = 0; q < 6; ++q) rd[d * 6 + q] = acc[d][q];
  }
  __syncthreads();
  if (rh == 0) {
    const float* rd = smem + ch * 1536 + lane * 24;
#pragma unroll
    for (int d = 0; d < 4; ++d)
#pragma unroll
      for (int q = 0; q < 6; ++q) acc[d][q] += rd[d * 6 + q];
  }
  if (wid == 2) {  // ch1, rh0: full mean sums in slot 5 after reduction
    const float a = ws[WS_A];
#pragma unroll
    for (int d = 0; d < 4; ++d) smem[3072 + lane * 4 + d] = a + acc[d][5];
  }
  __syncthreads();
  if (rh == 0) {
    float M[4];
#pragma unroll
    for (int d = 0; d < 4; ++d) M[d] = smem[3072 + lane * 4 + d];
#pragma unroll
    for (int q = 0; q < 5; ++q) {
      const int j = ch * 5 + q;
      float v = lin_b[j];
#pragma unroll
      for (int d = 0; d < 4; ++d)
        v += M[d] * (ws[WS_CST + d * 10 + j] + acc[d][q]);
      smem[3328 + lane * 12 + j] = v;
    }
  }
  __syncthreads();
  if (wid == 0) {
    float logits[10];
#pragma unroll
    for (int j = 0; j < 10; ++j) logits[j] = smem[3328 + lane * 12 + j];
    float mx = logits[0];
#pragma unroll
    for (int j = 1; j < 10; ++j) mx = fmaxf(mx, logits[j]);
    float se = 0.f;
#pragma unroll
    for (int j = 0; j < 10; ++j) se += __expf(logits[j] - mx);
    const float lse = mx + __logf(se);
    float* op = out + (size_t)(sbase + lane) * 10;
#pragma unroll
    for (int j = 0; j < 10; ++j) op[j] = logits[j] - lse;
  }
}

extern "C" void kernel_launch(void* const* d_in, const int* in_sizes, int n_in,
                              void* d_out, int out_size, void* d_ws, size_t ws_size,
                              hipStream_t stream) {
  (void)n_in; (void)ws_size; (void)out_size;
  const float* x = (const float*)d_in[0];
  const float* conv_w = (const float*)d_in[1];
  const float* conv_b = (const float*)d_in[2];
  // d_in[3]/d_in[4] (rotation/entangle) are dead: softmax over length-1 == 1.
  const float* lin_w = (const float*)d_in[5];
  const float* lin_b = (const float*)d_in[6];
  float* out = (float*)d_out;
  float* ws = (float*)d_ws;

  hipLaunchKernelGGL(qsac_prep, dim3(8), dim3(98), 0, stream,
                     conv_w, conv_b, lin_w, ws);

  const int B = in_sizes[0] / 784;  // 32768
  const int nblk = B / 64;          // 512 blocks x 256 threads
  hipLaunchKernelGGL(qsac_main, dim3(nblk), dim3(256), 0, stream,
                     x, ws, lin_b, out);
}

// Round 6
// 75.146 us; speedup vs baseline: 6.2108x; 1.1643x over previous
//
#include <hip/hip_runtime.h>
#include <cmath>

// QuanvolutionSelfAttentionClassifier on MI355X — round 6.
//
// Algebra (verified by R1/R2/R5 passes): softmax over length-1 axis == 1 ->
// attn_weights == mean_embeds (rotation/entangle params dead). With
// l = c*196 + p, embedding index d = p & 3; for input pixel (r,cc):
// d = (2*((r>>1)&1) + (cc>>1)) & 3.
//   logits[j] = lin_b[j] + sum_d M[d] * (cst[d][j] + T[d][j])
//   M[d]    = a + sum_pix x[pix]*gm(pix),   a = sum_c conv_b[c]/4
//   T[d][j] = sum_{pix: d(pix)==d} x[pix] * G[pix][j]
//
// R1/R2/R3/R5 all died on the same mechanism: G-operand delivery inflating
// live VGPRs -> scratch spill (R5: VGPR_Count=60, WRITE_SIZE=85MB — compiler
// does NOT scalarize "uniform" pointers; it clusters 42 vector loads/step).
// v6 delivers G via v_readlane: lanes 0..41 load the wave's 168-float G row
// slice as ONE per-lane float4 (coalesced, L2-resident), then compile-time
// readlane broadcasts each value into an SGPR consumed directly by v_fmac
// (single-SGPR-operand rule). 1 VMEM op/step instead of 42; G double-buffered
// one computing-step ahead (8 VGPR). sched_barrier(0) fences between pixel
// pairs bound live SGPRs (~12) and VGPRs (~130) — structurally spill-proof.
// x staging / planes / period-4 pipeline / epilogue are R5's verified code.

#define WS_A    9408
#define WS_CST  9409

__global__ void qsac_prep(const float* __restrict__ cw, const float* __restrict__ cb,
                          const float* __restrict__ lw, float* __restrict__ ws) {
  const int t = blockIdx.x * 98 + threadIdx.x;  // 8 x 98 = 784 pixels
  const int r = t / 28, cc = t - r * 28;
  const int kh = r & 1, kw = cc & 1;
  const int p = (r >> 1) * 14 + (cc >> 1);
  const float w0 = cw[(kh << 1) + kw],     w1 = cw[4 + (kh << 1) + kw],
              w2 = cw[8 + (kh << 1) + kw], w3 = cw[12 + (kh << 1) + kw];
  float g[10];
#pragma unroll
  for (int j = 0; j < 10; ++j)
    g[j] = w0 * lw[j * 784 + p]       + w1 * lw[j * 784 + 196 + p] +
           w2 * lw[j * 784 + 392 + p] + w3 * lw[j * 784 + 588 + p];
  const float gm = (w0 + w1 + w2 + w3) * (1.0f / 196.0f);
  // Layout: ws[ch*4704 + r*168 + cc*6 + k]; k<5 -> j=ch*5+k, k=5 -> 0|gm.
  const int pr = cc >> 1, e = cc & 1;
  float* d0 = ws + r * 168 + pr * 12 + e * 6;
  d0[0] = g[0]; d0[1] = g[1]; d0[2] = g[2]; d0[3] = g[3]; d0[4] = g[4]; d0[5] = 0.f;
  float* d1 = ws + 4704 + r * 168 + pr * 12 + e * 6;
  d1[0] = g[5]; d1[1] = g[6]; d1[2] = g[7]; d1[3] = g[8]; d1[4] = g[9]; d1[5] = gm;

  if (blockIdx.x == 0) {
    const int u = threadIdx.x;
    if (u < 40) {
      const int d = u / 10, j = u - (u / 10) * 10;
      const float b0 = cb[0], b1 = cb[1], b2 = cb[2], b3 = cb[3];
      float s = 0.f;
#pragma unroll 7
      for (int q = d; q < 196; q += 4)
        s += b0 * lw[j * 784 + q]       + b1 * lw[j * 784 + 196 + q] +
             b2 * lw[j * 784 + 392 + q] + b3 * lw[j * 784 + 588 + q];
      ws[WS_CST + u] = s;
    } else if (u == 40) {
      ws[WS_A] = (cb[0] + cb[1] + cb[2] + cb[3]) * 0.25f;
    }
  }
}

#define BAR()                                            \
  asm volatile("s_waitcnt lgkmcnt(0)" ::: "memory");     \
  __builtin_amdgcn_s_barrier();                          \
  asm volatile("" ::: "memory");

// Broadcast float I of the wave's G row (held as per-lane float4 over lanes
// 0..41) into an SGPR: compile-time component select + v_readlane.
template <int I>
__device__ __forceinline__ float rl(const float4& v) {
  constexpr int c = I & 3;
  const float f = (c == 0) ? v.x : (c == 1) ? v.y : (c == 2) ? v.z : v.w;
  return __int_as_float(__builtin_amdgcn_readlane(__float_as_int(f), I >> 2));
}

// One pixel-pair P (cols 2P,2P+1; shared d-class): 12 readlane + 12 fmac.
// sched_barrier(0) fence bounds live SGPR/VGPR across pairs.
#define PAIRR(P, PAR, GB)                                                     \
  {                                                                           \
    __builtin_amdgcn_sched_barrier(0);                                        \
    constexpr int DD = (2 * (PAR) + ((P)&3)) & 3;                             \
    const float xA = ((P)&1) ? tr[(P) >> 1].z : tr[(P) >> 1].x;               \
    const float xB = ((P)&1) ? tr[(P) >> 1].w : tr[(P) >> 1].y;               \
    acc[DD][0] += xA * rl<12 * (P) + 0>(GB);                                  \
    acc[DD][1] += xA * rl<12 * (P) + 1>(GB);                                  \
    acc[DD][2] += xA * rl<12 * (P) + 2>(GB);                                  \
    acc[DD][3] += xA * rl<12 * (P) + 3>(GB);                                  \
    acc[DD][4] += xA * rl<12 * (P) + 4>(GB);                                  \
    acc[DD][5] += xA * rl<12 * (P) + 5>(GB);                                  \
    acc[DD][0] += xB * rl<12 * (P) + 6>(GB);                                  \
    acc[DD][1] += xB * rl<12 * (P) + 7>(GB);                                  \
    acc[DD][2] += xB * rl<12 * (P) + 8>(GB);                                  \
    acc[DD][3] += xB * rl<12 * (P) + 9>(GB);                                  \
    acc[DD][4] += xB * rl<12 * (P) + 10>(GB);                                 \
    acc[DD][5] += xB * rl<12 * (P) + 11>(GB);                                 \
  }

// Computing part of a step: prefetch next computing row's G slice (one
// coalesced per-lane float4, consumed 2 steps later), read own sample's row
// from the plane, run 14 pair blocks.
#define COMPUTE(S, GCUR, GNXT)                                                \
  {                                                                           \
    const int rnx = (r_ + 2 < 28) ? r_ + 2 : 27;                              \
    GNXT = *reinterpret_cast<const float4*>(gsl + rnx * 168);                 \
    const float* rp = smem + ((S)&3) * 2304 + lane36;                         \
    float4 tr[7];                                                             \
    _Pragma("unroll") for (int mm = 0; mm < 7; ++mm)                          \
      tr[mm] = *reinterpret_cast<const float4*>(rp + mm * 4);                 \
    PAIRR(0, ((S) >> 1) & 1, GCUR)  PAIRR(1, ((S) >> 1) & 1, GCUR)            \
    PAIRR(2, ((S) >> 1) & 1, GCUR)  PAIRR(3, ((S) >> 1) & 1, GCUR)            \
    PAIRR(4, ((S) >> 1) & 1, GCUR)  PAIRR(5, ((S) >> 1) & 1, GCUR)            \
    PAIRR(6, ((S) >> 1) & 1, GCUR)  PAIRR(7, ((S) >> 1) & 1, GCUR)            \
    PAIRR(8, ((S) >> 1) & 1, GCUR)  PAIRR(9, ((S) >> 1) & 1, GCUR)            \
    PAIRR(10, ((S) >> 1) & 1, GCUR) PAIRR(11, ((S) >> 1) & 1, GCUR)           \
    PAIRR(12, ((S) >> 1) & 1, GCUR) PAIRR(13, ((S) >> 1) & 1, GCUR)           \
  }

// Step S (0..3): row r_ = rb+S (plane r_%4 == S). Stage row r_+3 into plane
// (S+3)&3 (last read at step S-1, protected by that step's barrier), reload
// its R-slot with row r_+7. Matching-parity waves compute. lgkmcnt(0)-only
// drain + raw barrier keeps global prefetch (vmcnt) in flight.
#define STEP(S, GCUR, GNXT)                                                   \
  {                                                                           \
    const int r_ = rb + (S);                                                  \
    if (r_ + 3 < 28) {                                                        \
      float* wp = smem + (((S) + 3) & 3) * 2304;                              \
      *reinterpret_cast<float4*>(wp + wadr1) = R1[((S) + 3) & 3];             \
      if (has2) *reinterpret_cast<float4*>(wp + wadr2) = R2[((S) + 3) & 3];   \
      if (r_ + 7 < 28) {                                                      \
        R1[((S) + 3) & 3] =                                                   \
            *reinterpret_cast<const float4*>(xg1 + (r_ + 7) * 28);            \
        if (has2)                                                             \
          R2[((S) + 3) & 3] =                                                 \
              *reinterpret_cast<const float4*>(xg2 + (r_ + 7) * 28);          \
      }                                                                       \
    }                                                                         \
    if (rh == ((S)&1)) { COMPUTE(S, GCUR, GNXT) }                             \
    BAR()                                                                     \
  }

__global__ __launch_bounds__(256, 2) void qsac_main(
    const float* __restrict__ x, const float* __restrict__ ws,
    const float* __restrict__ lin_b, float* __restrict__ out) {
  __shared__ float smem[4 * 2304];  // 36.9 KB: 4 x-planes [64][36]

  const int tid = threadIdx.x;
  const int lane = tid & 63;
  const int wid = __builtin_amdgcn_readfirstlane(tid >> 6);
  const int ch = wid >> 1, rh = wid & 1;
  const int sbase = blockIdx.x * 64;
  const int lane36 = lane * 36;
  // Per-lane G slice pointer: lane l<42 covers floats [4l,4l+4) of each
  // 168-float row of this wave's ch slice (lanes >=42 clamp to 0, unused).
  const float* gsl = ws + ch * 4704 + ((lane < 42) ? lane * 4 : 0);

  // x staging: chunk c -> sample s=c/7, 16B-piece m=c%7. c1 = tid (all),
  // c2 = tid+256 (tid<192; wave-uniform since 192 = 3*64). 448 chunks/row.
  const int s1 = tid / 7, m1 = tid - s1 * 7;
  const bool has2 = tid < 192;
  const int c2 = tid + 256;
  const int s2 = c2 / 7, m2 = c2 - s2 * 7;
  const float* xg1 = x + (size_t)(sbase + s1) * 784 + m1 * 4;
  const float* xg2 = x + (size_t)(sbase + (has2 ? s2 : 0)) * 784 + m2 * 4;
  const int wadr1 = s1 * 36 + m1 * 4;
  const int wadr2 = s2 * 36 + m2 * 4;

  // G double-buffer: Gb0 <- first computing row (row rh).
  float4 Gb0, Gb1;
  Gb0 = *reinterpret_cast<const float4*>(gsl + rh * 168);

  // Prologue: rows 0-2 -> planes 0-2; rows 3-6 -> R*[3],R*[0],R*[1],R*[2].
  float4 R1[4], R2[4];
  float4 a0 = *reinterpret_cast<const float4*>(xg1);
  float4 a1 = *reinterpret_cast<const float4*>(xg1 + 28);
  float4 a2 = *reinterpret_cast<const float4*>(xg1 + 56);
  float4 b0, b1, b2;
  if (has2) {
    b0 = *reinterpret_cast<const float4*>(xg2);
    b1 = *reinterpret_cast<const float4*>(xg2 + 28);
    b2 = *reinterpret_cast<const float4*>(xg2 + 56);
  }
  R1[3] = *reinterpret_cast<const float4*>(xg1 + 3 * 28);
  R1[0] = *reinterpret_cast<const float4*>(xg1 + 4 * 28);
  R1[1] = *reinterpret_cast<const float4*>(xg1 + 5 * 28);
  R1[2] = *reinterpret_cast<const float4*>(xg1 + 6 * 28);
  if (has2) {
    R2[3] = *reinterpret_cast<const float4*>(xg2 + 3 * 28);
    R2[0] = *reinterpret_cast<const float4*>(xg2 + 4 * 28);
    R2[1] = *reinterpret_cast<const float4*>(xg2 + 5 * 28);
    R2[2] = *reinterpret_cast<const float4*>(xg2 + 6 * 28);
  }
  *reinterpret_cast<float4*>(smem + 0 * 2304 + wadr1) = a0;
  *reinterpret_cast<float4*>(smem + 1 * 2304 + wadr1) = a1;
  *reinterpret_cast<float4*>(smem + 2 * 2304 + wadr1) = a2;
  if (has2) {
    *reinterpret_cast<float4*>(smem + 0 * 2304 + wadr2) = b0;
    *reinterpret_cast<float4*>(smem + 1 * 2304 + wadr2) = b1;
    *reinterpret_cast<float4*>(smem + 2 * 2304 + wadr2) = b2;
  }
  BAR()

  float acc[4][6];
#pragma unroll
  for (int d = 0; d < 4; ++d)
#pragma unroll
    for (int q = 0; q < 6; ++q) acc[d][q] = 0.f;

  // Computing rows per wave: r = rh, rh+2, ..., rh+26. Gbuf ping-pong:
  // even computing-step uses Gb0/prefetches Gb1, odd uses Gb1/prefetches Gb0.
#pragma unroll 1
  for (int it = 0; it < 7; ++it) {
    const int rb = it * 4;
    STEP(0, Gb0, Gb1) STEP(1, Gb0, Gb1) STEP(2, Gb1, Gb0) STEP(3, Gb1, Gb0)
  }

  // ---- epilogue (planes dead; overlay Red [0,3072) / Mld [3072,3328) /
  // L [3328,4096)) ----
  if (rh == 1) {
    float* rd = smem + ch * 1536 + lane * 24;
#pragma unroll
    for (int d = 0; d < 4; ++d)
#pragma unroll
      for (int q = 0; q < 6; ++q) rd[d * 6 + q] = acc[d][q];
  }
  __syncthreads();
  if (rh == 0) {
    const float* rd = smem + ch * 1536 + lane * 24;
#pragma unroll
    for (int d = 0; d < 4; ++d)
#pragma unroll
      for (int q = 0; q < 6; ++q) acc[d][q] += rd[d * 6 + q];
  }
  if (wid == 2) {  // ch1, rh0: full mean sums in slot 5 after reduction
    const float a = ws[WS_A];
#pragma unroll
    for (int d = 0; d < 4; ++d) smem[3072 + lane * 4 + d] = a + acc[d][5];
  }
  __syncthreads();
  if (rh == 0) {
    float M[4];
#pragma unroll
    for (int d = 0; d < 4; ++d) M[d] = smem[3072 + lane * 4 + d];
#pragma unroll
    for (int q = 0; q < 5; ++q) {
      const int j = ch * 5 + q;
      float v = lin_b[j];
#pragma unroll
      for (int d = 0; d < 4; ++d)
        v += M[d] * (ws[WS_CST + d * 10 + j] + acc[d][q]);
      smem[3328 + lane * 12 + j] = v;
    }
  }
  __syncthreads();
  if (wid == 0) {
    float logits[10];
#pragma unroll
    for (int j = 0; j < 10; ++j) logits[j] = smem[3328 + lane * 12 + j];
    float mx = logits[0];
#pragma unroll
    for (int j = 1; j < 10; ++j) mx = fmaxf(mx, logits[j]);
    float se = 0.f;
#pragma unroll
    for (int j = 0; j < 10; ++j) se += __expf(logits[j] - mx);
    const float lse = mx + __logf(se);
    float* op = out + (size_t)(sbase + lane) * 10;
#pragma unroll
    for (int j = 0; j < 10; ++j) op[j] = logits[j] - lse;
  }
}

extern "C" void kernel_launch(void* const* d_in, const int* in_sizes, int n_in,
                              void* d_out, int out_size, void* d_ws, size_t ws_size,
                              hipStream_t stream) {
  (void)n_in; (void)ws_size; (void)out_size;
  const float* x = (const float*)d_in[0];
  const float* conv_w = (const float*)d_in[1];
  const float* conv_b = (const float*)d_in[2];
  // d_in[3]/d_in[4] (rotation/entangle) are dead: softmax over length-1 == 1.
  const float* lin_w = (const float*)d_in[5];
  const float* lin_b = (const float*)d_in[6];
  float* out = (float*)d_out;
  float* ws = (float*)d_ws;

  hipLaunchKernelGGL(qsac_prep, dim3(8), dim3(98), 0, stream,
                     conv_w, conv_b, lin_w, ws);

  const int B = in_sizes[0] / 784;  // 32768
  const int nblk = B / 64;          // 512 blocks x 256 threads
  hipLaunchKernelGGL(qsac_main, dim3(nblk), dim3(256), 0, stream,
                     x, ws, lin_b, out);
}